// Round 1
// baseline (524.036 us; speedup 1.0000x reference)
//
#include <hip/hip_runtime.h>
#include <stdint.h>

#define S_LEN 4096
#define D_DIM 2048
#define NHEAD 16
#define HDIM  128

typedef short bf16x8 __attribute__((ext_vector_type(8)));
typedef float f32x4  __attribute__((ext_vector_type(4)));

__device__ __forceinline__ unsigned short f2bf(float x) {
  union { float f; unsigned u; } v; v.f = x;
  unsigned r = v.u + 0x7FFFu + ((v.u >> 16) & 1u);  // RNE
  return (unsigned short)(r >> 16);
}

__device__ __forceinline__ void gload_lds16(const void* g, void* l) {
  __builtin_amdgcn_global_load_lds(
      (const __attribute__((address_space(1))) unsigned int*)g,
      (__attribute__((address_space(3))) unsigned int*)l, 16, 0, 0);
}

// ---------------- fp32 -> bf16 convert (vectorized, memory-bound) ----------
__global__ __launch_bounds__(256) void cvt_bf16(const float* __restrict__ in,
                                                unsigned short* __restrict__ out,
                                                int n) {
  int i = (blockIdx.x * 256 + threadIdx.x) * 8;
  if (i >= n) return;
  float4 a = *(const float4*)(in + i);
  float4 b = *(const float4*)(in + i + 4);
  union { unsigned short s[8]; bf16x8 v; } o;
  o.s[0] = f2bf(a.x); o.s[1] = f2bf(a.y); o.s[2] = f2bf(a.z); o.s[3] = f2bf(a.w);
  o.s[4] = f2bf(b.x); o.s[5] = f2bf(b.y); o.s[6] = f2bf(b.z); o.s[7] = f2bf(b.w);
  *(bf16x8*)(out + i) = o.v;
}

// ---------------- bf16 GEMM, C[m,n] = sum_k A[m,k]*B[n,k] + bias[n] --------
// m97 structure: 128x128 tile, BK=32, 4 waves (2x2), 16 MFMA + 8 ds_read_b128
// + 4 global_load_lds_dwordx4 per K-step. Single LDS buffer, 2 barriers/step.
template<bool OUT_BF16>
__global__ __launch_bounds__(256, 2) void gemm_bt(
    const unsigned short* __restrict__ A, const unsigned short* __restrict__ B,
    const float* __restrict__ bias, void* __restrict__ Cout,
    int M, int N, int K) {
  __shared__ __attribute__((aligned(16))) unsigned short As[128 * 32];
  __shared__ __attribute__((aligned(16))) unsigned short Bs[128 * 32];
  const int m0 = blockIdx.y * 128, n0 = blockIdx.x * 128;
  const int tid = threadIdx.x, lane = tid & 63, wv = tid >> 6;
  const int wm = wv >> 1, wn = wv & 1;
  const int rA = lane & 15, kb = (lane >> 4) * 8;

  f32x4 acc[4][4];
#pragma unroll
  for (int i = 0; i < 4; ++i)
#pragma unroll
    for (int j = 0; j < 4; ++j)
#pragma unroll
      for (int r = 0; r < 4; ++r) acc[i][j][r] = 0.f;

  for (int k0 = 0; k0 < K; k0 += 32) {
    __syncthreads();
#pragma unroll
    for (int p = 0; p < 2; ++p) {  // each instr: 1KB = 16 rows x 64B
      const int rr = (wv * 2 + p) * 16 + (lane >> 2);
      const int cc = lane & 3;
      gload_lds16(A + (size_t)(m0 + rr) * K + k0 + cc * 8, As + (wv * 2 + p) * 512);
      gload_lds16(B + (size_t)(n0 + rr) * K + k0 + cc * 8, Bs + (wv * 2 + p) * 512);
    }
    __syncthreads();
    bf16x8 af[4], bfr[4];
#pragma unroll
    for (int i = 0; i < 4; ++i)
      af[i] = *(const bf16x8*)(As + (wm * 64 + i * 16 + rA) * 32 + kb);
#pragma unroll
    for (int j = 0; j < 4; ++j)
      bfr[j] = *(const bf16x8*)(Bs + (wn * 64 + j * 16 + rA) * 32 + kb);
#pragma unroll
    for (int i = 0; i < 4; ++i)
#pragma unroll
      for (int j = 0; j < 4; ++j)
        acc[i][j] = __builtin_amdgcn_mfma_f32_16x16x32_bf16(af[i], bfr[j], acc[i][j], 0, 0, 0);
  }

  // epilogue: C col = lane&15, row = (lane>>4)*4 + reg  (verified m89/m91)
  const int cR = (lane >> 4) * 4, cC = lane & 15;
#pragma unroll
  for (int j = 0; j < 4; ++j) {
    const int col = n0 + wn * 64 + j * 16 + cC;
    const float bv = bias[col];
#pragma unroll
    for (int i = 0; i < 4; ++i) {
      const int row0 = m0 + wm * 64 + i * 16 + cR;
#pragma unroll
      for (int r = 0; r < 4; ++r) {
        const float v = acc[i][j][r] + bv;
        if (OUT_BF16)
          ((unsigned short*)Cout)[(size_t)(row0 + r) * N + col] = f2bf(v);
        else
          ((float*)Cout)[(size_t)(row0 + r) * N + col] = v;
      }
    }
  }
}

// ---------------- causal flash attention -----------------------------------
// Block: 4 waves x 32 q-rows = 128 q-rows, one head. KT=32 keys/tile.
// K tile: global_load_lds with pre-swizzled global source (XOR chunk^(row&7))
//   so QK^T B-frag ds_read_b128 is bank-conflict-free.
// V tile: reg-staged TRANSPOSED into LDS [hd][k], stride 56 (112B: 2-way=free).
// P round-trips through per-wave LDS [q][k] stride 56 to reach A-frag layout.
__global__ __launch_bounds__(256, 2) void attn_fwd(
    const unsigned short* __restrict__ Qb, const unsigned short* __restrict__ Kb,
    const unsigned short* __restrict__ Vb, unsigned short* __restrict__ Ob) {
  __shared__ __attribute__((aligned(16))) unsigned short Ks[32 * 128];
  __shared__ __attribute__((aligned(16))) unsigned short Vt[128 * 56];
  __shared__ __attribute__((aligned(16))) unsigned short Ps[4][32 * 56];
  const int h = blockIdx.y;
  const int bx = blockIdx.x;
  const int qi = (h < 8) ? bx : (31 - bx);  // heavy+light pairing per CU
  const int q0 = qi * 128;
  const int tid = threadIdx.x, lane = tid & 63, wv = tid >> 6;
  const int rA = lane & 15, kg = lane >> 4, kb = kg * 8;

  // Q fragments hoisted to registers: rows q0+wv*32+i*16+rA, hd = kf*32+kb
  bf16x8 qf[2][4];
#pragma unroll
  for (int i = 0; i < 2; ++i)
#pragma unroll
    for (int kf = 0; kf < 4; ++kf)
      qf[i][kf] = *(const bf16x8*)(Qb + (size_t)(q0 + wv * 32 + i * 16 + rA) * D_DIM
                                   + h * HDIM + kf * 32 + kb);

  float m_r[2][4], l_r[2][4];
  f32x4 oacc[2][8];
#pragma unroll
  for (int i = 0; i < 2; ++i)
#pragma unroll
    for (int r = 0; r < 4; ++r) { m_r[i][r] = -__builtin_inff(); l_r[i][r] = 0.f; }
#pragma unroll
  for (int i = 0; i < 2; ++i)
#pragma unroll
    for (int nf = 0; nf < 8; ++nf)
#pragma unroll
      for (int r = 0; r < 4; ++r) oacc[i][nf][r] = 0.f;

  const int nt = q0 / 32 + 4;                // tiles cover keys 0..q0+127
  const int wqmax = q0 + wv * 32 + 31;       // this wave's last valid key
  const float scale = 0.08838834764831845f;  // 1/sqrt(128)

  for (int kt = 0; kt < nt; ++kt) {
    const int k0 = kt * 32;
    __syncthreads();  // previous tile's compute done; LDS reusable
    // --- stage K (swizzled source -> linear LDS dest) ---
#pragma unroll
    for (int p = 0; p < 2; ++p) {  // 1KB per instr = 4 key-rows x 256B
      const int r = (wv * 2 + p) * 4 + kg;
      const int c = rA ^ (r & 7);
      gload_lds16(Kb + (size_t)(k0 + r) * D_DIM + h * HDIM + c * 8,
                  Ks + (wv * 2 + p) * 512);
    }
    // --- stage V transposed ---
    {
      const int kv = tid & 31;
      const int hd0 = (tid >> 5) * 16;
      const unsigned short* src = Vb + (size_t)(k0 + kv) * D_DIM + h * HDIM + hd0;
      union { uint4 q[2]; unsigned short s[16]; } vvv;
      vvv.q[0] = *(const uint4*)(src);
      vvv.q[1] = *(const uint4*)(src + 8);
#pragma unroll
      for (int e = 0; e < 16; ++e) Vt[(hd0 + e) * 56 + kv] = vvv.s[e];
    }
    __syncthreads();
    if (k0 > wqmax) continue;  // fully-masked tile for this wave

    // --- QK^T: S[q][key] ---
    f32x4 sacc[2][2];
#pragma unroll
    for (int i = 0; i < 2; ++i)
#pragma unroll
      for (int nj = 0; nj < 2; ++nj)
#pragma unroll
        for (int r = 0; r < 4; ++r) sacc[i][nj][r] = 0.f;
#pragma unroll
    for (int kf = 0; kf < 4; ++kf) {
      bf16x8 kfr[2];
#pragma unroll
      for (int nj = 0; nj < 2; ++nj) {
        const int row = nj * 16 + rA;
        const int slot = (kg + kf * 4) ^ (row & 7);
        kfr[nj] = *(const bf16x8*)(Ks + row * 128 + slot * 8);
      }
#pragma unroll
      for (int i = 0; i < 2; ++i)
#pragma unroll
        for (int nj = 0; nj < 2; ++nj)
          sacc[i][nj] = __builtin_amdgcn_mfma_f32_16x16x32_bf16(qf[i][kf], kfr[nj], sacc[i][nj], 0, 0, 0);
    }

    // --- online softmax (rows distributed: (i,reg); cols across lane&15) ---
    float pv2[2][2][4], corr[2][4];
#pragma unroll
    for (int i = 0; i < 2; ++i) {
#pragma unroll
      for (int r = 0; r < 4; ++r) {
        const int q = q0 + wv * 32 + i * 16 + kg * 4 + r;
        float t0 = sacc[i][0][r] * scale;
        float t1 = sacc[i][1][r] * scale;
        if (k0 + rA > q)      t0 = -__builtin_inff();
        if (k0 + 16 + rA > q) t1 = -__builtin_inff();
        float mx = fmaxf(t0, t1);
        mx = fmaxf(mx, __shfl_xor(mx, 1));
        mx = fmaxf(mx, __shfl_xor(mx, 2));
        mx = fmaxf(mx, __shfl_xor(mx, 4));
        mx = fmaxf(mx, __shfl_xor(mx, 8));
        const float mn = fmaxf(m_r[i][r], mx);
        const float c = __expf(m_r[i][r] - mn);
        m_r[i][r] = mn;
        corr[i][r] = c;
        const float p0 = __expf(t0 - mn);
        const float p1 = __expf(t1 - mn);
        float rs = p0 + p1;
        rs += __shfl_xor(rs, 1);
        rs += __shfl_xor(rs, 2);
        rs += __shfl_xor(rs, 4);
        rs += __shfl_xor(rs, 8);
        l_r[i][r] = l_r[i][r] * c + rs;
        pv2[i][0][r] = p0; pv2[i][1][r] = p1;
      }
    }
    // rescale O, write P (bf16) to per-wave LDS
#pragma unroll
    for (int i = 0; i < 2; ++i) {
#pragma unroll
      for (int nf = 0; nf < 8; ++nf)
#pragma unroll
        for (int r = 0; r < 4; ++r) oacc[i][nf][r] *= corr[i][r];
#pragma unroll
      for (int r = 0; r < 4; ++r) {
        const int prow = i * 16 + kg * 4 + r;
        Ps[wv][prow * 56 + rA]      = f2bf(pv2[i][0][r]);
        Ps[wv][prow * 56 + 16 + rA] = f2bf(pv2[i][1][r]);
      }
    }
    // --- PV: O[q][hd] += P[q][k] * V[k][hd]  (B-frag from transposed Vt) ---
    bf16x8 pf[2];
#pragma unroll
    for (int i = 0; i < 2; ++i)
      pf[i] = *(const bf16x8*)(&Ps[wv][(i * 16 + rA) * 56 + kb]);
#pragma unroll
    for (int nf = 0; nf < 8; ++nf) {
      bf16x8 vf = *(const bf16x8*)(Vt + (nf * 16 + rA) * 56 + kb);
#pragma unroll
      for (int i = 0; i < 2; ++i)
        oacc[i][nf] = __builtin_amdgcn_mfma_f32_16x16x32_bf16(pf[i], vf, oacc[i][nf], 0, 0, 0);
    }
  }

  // epilogue: normalize and store bf16 [s][h*128+hd]
#pragma unroll
  for (int i = 0; i < 2; ++i) {
    float inv[4];
#pragma unroll
    for (int r = 0; r < 4; ++r) inv[r] = 1.f / l_r[i][r];
#pragma unroll
    for (int nf = 0; nf < 8; ++nf)
#pragma unroll
      for (int r = 0; r < 4; ++r) {
        const int q = q0 + wv * 32 + i * 16 + kg * 4 + r;
        Ob[(size_t)q * D_DIM + h * HDIM + nf * 16 + rA] = f2bf(oacc[i][nf][r] * inv[r]);
      }
  }
}

extern "C" void kernel_launch(void* const* d_in, const int* in_sizes, int n_in,
                              void* d_out, int out_size, void* d_ws, size_t ws_size,
                              hipStream_t stream) {
  const float* X  = (const float*)d_in[0];
  const float* Wq = (const float*)d_in[1];
  const float* bq = (const float*)d_in[2];
  const float* Wk = (const float*)d_in[3];
  const float* bk = (const float*)d_in[4];
  const float* Wv = (const float*)d_in[5];
  const float* bv = (const float*)d_in[6];
  const float* Wo = (const float*)d_in[7];
  const float* bo = (const float*)d_in[8];
  float* out = (float*)d_out;

  unsigned short* ws = (unsigned short*)d_ws;
  const size_t SD = (size_t)S_LEN * D_DIM;  // 8388608
  const size_t DD = (size_t)D_DIM * D_DIM;  // 4194304
  unsigned short* Xb  = ws;
  unsigned short* Wqb = Xb + SD;
  unsigned short* Wkb = Wqb + DD;
  unsigned short* Wvb = Wkb + DD;
  unsigned short* Wob = Wvb + DD;
  unsigned short* Qb  = Wob + DD;
  unsigned short* Kb  = Qb + SD;
  unsigned short* Vb  = Kb + SD;
  unsigned short* AOb = Vb + SD;  // total 112 MB of d_ws

  cvt_bf16<<<(int)(SD / 8 / 256), 256, 0, stream>>>(X, Xb, (int)SD);
  cvt_bf16<<<(int)(DD / 8 / 256), 256, 0, stream>>>(Wq, Wqb, (int)DD);
  cvt_bf16<<<(int)(DD / 8 / 256), 256, 0, stream>>>(Wk, Wkb, (int)DD);
  cvt_bf16<<<(int)(DD / 8 / 256), 256, 0, stream>>>(Wv, Wvb, (int)DD);
  cvt_bf16<<<(int)(DD / 8 / 256), 256, 0, stream>>>(Wo, Wob, (int)DD);

  dim3 gg(D_DIM / 128, S_LEN / 128);  // (16, 32)
  gemm_bt<true><<<gg, 256, 0, stream>>>(Xb, Wqb, bq, Qb, S_LEN, D_DIM, D_DIM);
  gemm_bt<true><<<gg, 256, 0, stream>>>(Xb, Wkb, bk, Kb, S_LEN, D_DIM, D_DIM);
  gemm_bt<true><<<gg, 256, 0, stream>>>(Xb, Wvb, bv, Vb, S_LEN, D_DIM, D_DIM);

  attn_fwd<<<dim3(32, 16), 256, 0, stream>>>(Qb, Kb, Vb, AOb);

  gemm_bt<false><<<gg, 256, 0, stream>>>(AOb, Wob, bo, out, S_LEN, D_DIM, D_DIM);
}

// Round 2
// 404.792 us; speedup vs baseline: 1.2946x; 1.2946x over previous
//
#include <hip/hip_runtime.h>
#include <stdint.h>

#define S_LEN 4096
#define D_DIM 2048
#define NHEAD 16
#define HDIM  128

typedef short bf16x8 __attribute__((ext_vector_type(8)));
typedef float f32x4  __attribute__((ext_vector_type(4)));
typedef float f32x16 __attribute__((ext_vector_type(16)));

__device__ __forceinline__ unsigned short f2bf(float x) {
  union { float f; unsigned u; } v; v.f = x;
  unsigned r = v.u + 0x7FFFu + ((v.u >> 16) & 1u);  // RNE
  return (unsigned short)(r >> 16);
}

__device__ __forceinline__ unsigned cvtpk_bf16(float lo, float hi_) {
  unsigned r;
  asm("v_cvt_pk_bf16_f32 %0, %1, %2" : "=v"(r) : "v"(lo), "v"(hi_));
  return r;
}

__device__ __forceinline__ void gload_lds16(const void* g, void* l) {
  __builtin_amdgcn_global_load_lds(
      (const __attribute__((address_space(1))) unsigned int*)g,
      (__attribute__((address_space(3))) unsigned int*)l, 16, 0, 0);
}

// ---------------- fp32 -> bf16 convert (vectorized, memory-bound) ----------
__global__ __launch_bounds__(256) void cvt_bf16(const float* __restrict__ in,
                                                unsigned short* __restrict__ out,
                                                int n) {
  int i = (blockIdx.x * 256 + threadIdx.x) * 8;
  if (i >= n) return;
  float4 a = *(const float4*)(in + i);
  float4 b = *(const float4*)(in + i + 4);
  union { unsigned short s[8]; bf16x8 v; } o;
  o.s[0] = f2bf(a.x); o.s[1] = f2bf(a.y); o.s[2] = f2bf(a.z); o.s[3] = f2bf(a.w);
  o.s[4] = f2bf(b.x); o.s[5] = f2bf(b.y); o.s[6] = f2bf(b.z); o.s[7] = f2bf(b.w);
  *(bf16x8*)(out + i) = o.v;
}

// ---------------- bf16 GEMM, C[m,n] = sum_k A[m,k]*B[n,k] + bias[n] --------
template<bool OUT_BF16>
__global__ __launch_bounds__(256, 2) void gemm_bt(
    const unsigned short* __restrict__ A, const unsigned short* __restrict__ B,
    const float* __restrict__ bias, void* __restrict__ Cout,
    int M, int N, int K) {
  __shared__ __attribute__((aligned(16))) unsigned short As[128 * 32];
  __shared__ __attribute__((aligned(16))) unsigned short Bs[128 * 32];
  const int m0 = blockIdx.y * 128, n0 = blockIdx.x * 128;
  const int tid = threadIdx.x, lane = tid & 63, wv = tid >> 6;
  const int wm = wv >> 1, wn = wv & 1;
  const int rA = lane & 15, kb = (lane >> 4) * 8;

  f32x4 acc[4][4];
#pragma unroll
  for (int i = 0; i < 4; ++i)
#pragma unroll
    for (int j = 0; j < 4; ++j)
#pragma unroll
      for (int r = 0; r < 4; ++r) acc[i][j][r] = 0.f;

  for (int k0 = 0; k0 < K; k0 += 32) {
    __syncthreads();
#pragma unroll
    for (int p = 0; p < 2; ++p) {
      const int rr = (wv * 2 + p) * 16 + (lane >> 2);
      const int cc = lane & 3;
      gload_lds16(A + (size_t)(m0 + rr) * K + k0 + cc * 8, As + (wv * 2 + p) * 512);
      gload_lds16(B + (size_t)(n0 + rr) * K + k0 + cc * 8, Bs + (wv * 2 + p) * 512);
    }
    __syncthreads();
    bf16x8 af[4], bfr[4];
#pragma unroll
    for (int i = 0; i < 4; ++i)
      af[i] = *(const bf16x8*)(As + (wm * 64 + i * 16 + rA) * 32 + kb);
#pragma unroll
    for (int j = 0; j < 4; ++j)
      bfr[j] = *(const bf16x8*)(Bs + (wn * 64 + j * 16 + rA) * 32 + kb);
#pragma unroll
    for (int i = 0; i < 4; ++i)
#pragma unroll
      for (int j = 0; j < 4; ++j)
        acc[i][j] = __builtin_amdgcn_mfma_f32_16x16x32_bf16(af[i], bfr[j], acc[i][j], 0, 0, 0);
  }

  const int cR = (lane >> 4) * 4, cC = lane & 15;
#pragma unroll
  for (int j = 0; j < 4; ++j) {
    const int col = n0 + wn * 64 + j * 16 + cC;
    const float bv = bias[col];
#pragma unroll
    for (int i = 0; i < 4; ++i) {
      const int row0 = m0 + wm * 64 + i * 16 + cR;
#pragma unroll
      for (int r = 0; r < 4; ++r) {
        const float v = acc[i][j][r] + bv;
        if (OUT_BF16)
          ((unsigned short*)Cout)[(size_t)(row0 + r) * N + col] = f2bf(v);
        else
          ((float*)Cout)[(size_t)(row0 + r) * N + col] = v;
      }
    }
  }
}

// ---------------- causal flash attention, swapped-QK^T 32x32 structure -----
// 4 warps x 32 q-rows = 128 q/block; KVBLK=64.
// QK^T computed as mfma(K, Q) -> S^T: lane holds col q=lane&31, 32 k-vals in
// regs (crow(r,hi) = (r&3)+8*(r>>2)+4*hi). Softmax fully in-register:
// 31-op tree + one shfl_xor(32). P->bf16 A-frags via v_cvt_pk + half-swap.
// K staged by global_load_lds w=16 with pre-swizzled source (chunk^(row&7));
// V reg-staged transposed [hd][key] with the same XOR swizzle.
__global__ __launch_bounds__(256, 2) void attn_fwd2(
    const unsigned short* __restrict__ Qb, const unsigned short* __restrict__ Kb,
    const unsigned short* __restrict__ Vb, unsigned short* __restrict__ Ob) {
  __shared__ __attribute__((aligned(16))) unsigned short Ks[64 * 128];
  __shared__ __attribute__((aligned(16))) unsigned short Vt[128 * 64];
  const int h = blockIdx.y, bx = blockIdx.x;
  const int qi = (h < 8) ? bx : (31 - bx);  // heavy+light pairing per CU
  const int q0 = qi * 128;
  const int tid = threadIdx.x, lane = tid & 63, wv = tid >> 6;
  const int qc = lane & 31, hi = lane >> 5;
  const int q0w = q0 + wv * 32;
  const int myq = q0w + qc;

  // Q as B-operand fragments: qf[sl] = Q[myq][sl*16 + hi*8 .. +8]
  bf16x8 qf[8];
#pragma unroll
  for (int sl = 0; sl < 8; ++sl)
    qf[sl] = *(const bf16x8*)(Qb + (size_t)myq * D_DIM + h * HDIM + sl * 16 + hi * 8);

  f32x16 oacc[4];
#pragma unroll
  for (int nf = 0; nf < 4; ++nf)
#pragma unroll
    for (int r = 0; r < 16; ++r) oacc[nf][r] = 0.f;
  float mh = -3.0e38f, l = 0.f;
  const float c1 = 0.08838834764831845f * 1.44269504089f;  // scale * log2(e)

  const int nt = q0 / 64 + 2;       // 64-key tiles covering 0..q0+127
  const int wqmax = q0w + 31;

  for (int kt = 0; kt < nt; ++kt) {
    const int k0 = kt * 64;
    __syncthreads();
    // --- stage K: 16KB, pre-swizzled global source -> linear LDS dest ---
#pragma unroll
    for (int p = 0; p < 4; ++p) {
      const int ob = wv * 4096 + p * 1024;   // wave-uniform LDS base (bytes)
      const int o = ob + lane * 16;          // per-lane linear byte offset
      const int r = o >> 8, c = (o >> 4) & 15;
      gload_lds16(Kb + (size_t)(k0 + r) * D_DIM + h * HDIM + (c ^ (r & 7)) * 8,
                  Ks + ob / 2);
    }
    // --- stage V transposed: Vt[hd][key], u32-packed key pairs, swizzled ---
    {
      const int kp = tid & 31, hb = (tid >> 5) * 16;
      const unsigned short* s0 = Vb + (size_t)(k0 + 2 * kp) * D_DIM + h * HDIM + hb;
      union { uint4 u[2]; unsigned short s[16]; } r0, r1;
      r0.u[0] = *(const uint4*)s0;           r0.u[1] = *(const uint4*)(s0 + 8);
      r1.u[0] = *(const uint4*)(s0 + D_DIM); r1.u[1] = *(const uint4*)(s0 + D_DIM + 8);
#pragma unroll
      for (int w = 0; w < 16; ++w) {
        const int hd = hb + w;
        const unsigned val = (unsigned)r0.s[w] | ((unsigned)r1.s[w] << 16);
        *(unsigned*)((char*)Vt + hd * 128 + (((kp >> 2) ^ (hd & 7)) << 4) + ((kp & 3) << 2)) = val;
      }
    }
    __syncthreads();
    if (k0 > wqmax) continue;   // wave-uniform skip of fully-masked tiles

    // --- QK^T (swapped): sacc[kb] = S^T[32 keys][32 q] ---
    f32x16 sacc[2];
#pragma unroll
    for (int kb = 0; kb < 2; ++kb)
#pragma unroll
      for (int r = 0; r < 16; ++r) sacc[kb][r] = 0.f;
#pragma unroll
    for (int sl = 0; sl < 8; ++sl) {
#pragma unroll
      for (int kb = 0; kb < 2; ++kb) {
        const int row = kb * 32 + qc;
        bf16x8 kfr = *(const bf16x8*)((const char*)Ks + row * 256 +
                                      (((2 * sl + hi) ^ (qc & 7)) << 4));
        sacc[kb] = __builtin_amdgcn_mfma_f32_32x32x16_bf16(kfr, qf[sl], sacc[kb], 0, 0, 0);
      }
    }

    // --- in-register online softmax (log2 domain) ---
    const bool needmask = (k0 + 63 > q0w);
    const int dq = myq - k0;  // key valid iff kb*32 + crow <= dq
#pragma unroll
    for (int kb = 0; kb < 2; ++kb)
#pragma unroll
      for (int r = 0; r < 16; ++r) {
        float v = sacc[kb][r] * c1;
        if (needmask) {
          const int kk = kb * 32 + (r & 3) + 8 * (r >> 2) + 4 * hi;
          v = (kk <= dq) ? v : -3.0e38f;
        }
        sacc[kb][r] = v;
      }
    float mx = sacc[0][0];
#pragma unroll
    for (int kb = 0; kb < 2; ++kb)
#pragma unroll
      for (int r = 0; r < 16; ++r) mx = fmaxf(mx, sacc[kb][r]);
    mx = fmaxf(mx, __shfl_xor(mx, 32));
    if (!__all(mx <= mh + 11.5f)) {  // defer-max (T13)
      const float mnew = fmaxf(mh, mx);
      const float corr = exp2f(mh - mnew);
      mh = mnew;
      l *= corr;
#pragma unroll
      for (int r = 0; r < 16; ++r) {
        const float cr = __shfl(corr, (r & 3) + 8 * (r >> 2) + 4 * hi);
#pragma unroll
        for (int nf = 0; nf < 4; ++nf) oacc[nf][r] *= cr;
      }
    }
    float rs = 0.f;
#pragma unroll
    for (int kb = 0; kb < 2; ++kb)
#pragma unroll
      for (int r = 0; r < 16; ++r) {
        const float p = exp2f(sacc[kb][r] - mh);
        sacc[kb][r] = p;
        rs += p;
      }
    rs += __shfl_xor(rs, 32);
    l += rs;

    // --- P -> bf16 A-fragments (cvt_pk + half-swap) ---
    bf16x8 pa[4];
#pragma unroll
    for (int kb = 0; kb < 2; ++kb)
#pragma unroll
      for (int s = 0; s < 2; ++s) {
        const int b = s * 8;
        unsigned pk0 = cvtpk_bf16(sacc[kb][b + 0], sacc[kb][b + 1]);
        unsigned pk1 = cvtpk_bf16(sacc[kb][b + 2], sacc[kb][b + 3]);
        unsigned pk2 = cvtpk_bf16(sacc[kb][b + 4], sacc[kb][b + 5]);
        unsigned pk3 = cvtpk_bf16(sacc[kb][b + 6], sacc[kb][b + 7]);
        const unsigned sw0 = (unsigned)__shfl_xor((int)pk0, 32);
        const unsigned sw1 = (unsigned)__shfl_xor((int)pk1, 32);
        const unsigned sw2 = (unsigned)__shfl_xor((int)pk2, 32);
        const unsigned sw3 = (unsigned)__shfl_xor((int)pk3, 32);
        union { unsigned u[4]; bf16x8 v; } f;
        if (hi) { f.u[0] = sw2; f.u[1] = sw3; f.u[2] = pk2; f.u[3] = pk3; }
        else    { f.u[0] = pk0; f.u[1] = pk1; f.u[2] = sw0; f.u[3] = sw1; }
        pa[kb * 2 + s] = f.v;
      }

    // --- PV: oacc[nf] += P(32q x 16k) * V(16k x 32hd) ---
#pragma unroll
    for (int nf = 0; nf < 4; ++nf) {
      const int hd = 32 * nf + qc;
#pragma unroll
      for (int ks = 0; ks < 4; ++ks) {
        bf16x8 vf = *(const bf16x8*)((const char*)Vt + hd * 128 +
                                     (((2 * ks + hi) ^ (qc & 7)) << 4));
        oacc[nf] = __builtin_amdgcn_mfma_f32_32x32x16_bf16(pa[ks], vf, oacc[nf], 0, 0, 0);
      }
    }
  }

  // --- epilogue: normalize by l, store bf16 ---
  const float linv = 1.0f / l;
#pragma unroll
  for (int r = 0; r < 16; ++r) {
    const float li = __shfl(linv, (r & 3) + 8 * (r >> 2) + 4 * hi);
    const int q = q0w + (r & 3) + 8 * (r >> 2) + 4 * hi;
#pragma unroll
    for (int nf = 0; nf < 4; ++nf)
      Ob[(size_t)q * D_DIM + h * HDIM + 32 * nf + qc] = f2bf(oacc[nf][r] * li);
  }
}

extern "C" void kernel_launch(void* const* d_in, const int* in_sizes, int n_in,
                              void* d_out, int out_size, void* d_ws, size_t ws_size,
                              hipStream_t stream) {
  const float* X  = (const float*)d_in[0];
  const float* Wq = (const float*)d_in[1];
  const float* bq = (const float*)d_in[2];
  const float* Wk = (const float*)d_in[3];
  const float* bk = (const float*)d_in[4];
  const float* Wv = (const float*)d_in[5];
  const float* bv = (const float*)d_in[6];
  const float* Wo = (const float*)d_in[7];
  const float* bo = (const float*)d_in[8];
  float* out = (float*)d_out;

  unsigned short* ws = (unsigned short*)d_ws;
  const size_t SD = (size_t)S_LEN * D_DIM;
  const size_t DD = (size_t)D_DIM * D_DIM;
  unsigned short* Xb  = ws;
  unsigned short* Wqb = Xb + SD;
  unsigned short* Wkb = Wqb + DD;
  unsigned short* Wvb = Wkb + DD;
  unsigned short* Wob = Wvb + DD;
  unsigned short* Qb  = Wob + DD;
  unsigned short* Kb  = Qb + SD;
  unsigned short* Vb  = Kb + SD;
  unsigned short* AOb = Vb + SD;

  cvt_bf16<<<(int)(SD / 8 / 256), 256, 0, stream>>>(X, Xb, (int)SD);
  cvt_bf16<<<(int)(DD / 8 / 256), 256, 0, stream>>>(Wq, Wqb, (int)DD);
  cvt_bf16<<<(int)(DD / 8 / 256), 256, 0, stream>>>(Wk, Wkb, (int)DD);
  cvt_bf16<<<(int)(DD / 8 / 256), 256, 0, stream>>>(Wv, Wvb, (int)DD);
  cvt_bf16<<<(int)(DD / 8 / 256), 256, 0, stream>>>(Wo, Wob, (int)DD);

  dim3 gg(D_DIM / 128, S_LEN / 128);
  gemm_bt<true><<<gg, 256, 0, stream>>>(Xb, Wqb, bq, Qb, S_LEN, D_DIM, D_DIM);
  gemm_bt<true><<<gg, 256, 0, stream>>>(Xb, Wkb, bk, Kb, S_LEN, D_DIM, D_DIM);
  gemm_bt<true><<<gg, 256, 0, stream>>>(Xb, Wvb, bv, Vb, S_LEN, D_DIM, D_DIM);

  attn_fwd2<<<dim3(32, 16), 256, 0, stream>>>(Qb, Kb, Vb, AOb);

  gemm_bt<false><<<gg, 256, 0, stream>>>(AOb, Wob, bo, out, S_LEN, D_DIM, D_DIM);
}